// Round 14
// baseline (476.935 us; speedup 1.0000x reference)
//
#include <hip/hip_runtime.h>
#include <stdint.h>

#define B_ 8
#define S_ 128
#define R_ 41
#define F_ 768
#define NH_ 8
#define HID_ 96
#define BS_ (B_*S_)
#define SM_SCALE 256.0f
#define NG_ 21   // split-K groups in kOutGemm (20 x 2r + 1 x 1r)
#define NWV_ (R_*12)

typedef _Float16 f16;
typedef _Float16 f16x8 __attribute__((ext_vector_type(8)));
typedef _Float16 f16x4 __attribute__((ext_vector_type(4)));
typedef _Float16 f16x2 __attribute__((ext_vector_type(2)));
typedef float f32x4 __attribute__((ext_vector_type(4)));
typedef float f32x2 __attribute__((ext_vector_type(2)));

#define GLD16(gp, lp) __builtin_amdgcn_global_load_lds((const __attribute__((address_space(1))) uint32_t*)(gp), (__attribute__((address_space(3))) uint32_t*)(lp), 16, 0, 0)

__device__ __forceinline__ float wredsum(float v){
  #pragma unroll
  for (int o=32;o;o>>=1) v += __shfl_down(v,o,64);
  return v;
}

// ================ kPrep: input-only work (R13 body) ================
__global__ __launch_bounds__(256) void kPrep(const float* __restrict__ w_rgcn, const float* __restrict__ score_w,
                                             const float* __restrict__ wk, const float* __restrict__ x,
                                             const float* __restrict__ qin, const float* __restrict__ wq,
                                             f16* __restrict__ wT0, f16* __restrict__ wT1,
                                             float* __restrict__ v0, float* __restrict__ v1,
                                             f16* __restrict__ wkT, f16* __restrict__ h16T,
                                             float* __restrict__ qxpart) {
  __shared__ float sbuf[2*64*68];
  int bid = blockIdx.x;
  int tid = threadIdx.x;
  if (bid < 2*NWV_) {
    int l = (bid >= NWV_);
    int sub = bid - l*NWV_;
    const float* w = w_rgcn + (size_t)l*R_*F_*F_;
    const float* sw = score_w + l*F_;
    f16* wT = l ? wT1 : wT0;
    float* v = l ? v1 : v0;
    int it = sub % 12, r = sub / 12;
    int ri = tid >> 2, c = tid & 3;
    const float* srow = w + ((size_t)r*F_ + (it*64 + ri))*F_ + c*16;
    float vacc = 0.f;
    f32x4 cur[4];
    #pragma unroll
    for (int j=0;j<4;j++) cur[j] = *(const f32x4*)(srow + j*4);
    int ro = tid >> 2;
    for (int ot = 0; ot < 12; ++ot) {
      float* buf = &sbuf[(ot&1)*64*68];
      f32x4 nxt[4];
      if (ot < 11) {
        const float* nsrc = srow + (ot+1)*64;
        #pragma unroll
        for (int j=0;j<4;j++) nxt[j] = *(const f32x4*)(nsrc + j*4);
      }
      const float* swp = sw + ot*64 + c*16;
      #pragma unroll
      for (int j=0;j<4;j++){
        f32x4 s4 = *(const f32x4*)(swp + j*4);
        vacc += cur[j].x*s4.x + cur[j].y*s4.y + cur[j].z*s4.z + cur[j].w*s4.w;
      }
      #pragma unroll
      for (int j=0;j<4;j++) *(f32x4*)&buf[ri*68 + c*16 + j*4] = cur[j];
      __syncthreads();
      f16 outv[16];
      #pragma unroll
      for (int j=0;j<16;j++) outv[j] = (f16)buf[(c*16+j)*68 + ro];
      f16* dst = wT + ((size_t)r*F_ + (ot*64+ro))*F_ + it*64 + c*16;
      *(f16x8*)dst = *(f16x8*)&outv[0];
      *(f16x8*)(dst+8) = *(f16x8*)&outv[8];
      if (ot < 11) {
        #pragma unroll
        for (int j=0;j<4;j++) cur[j] = nxt[j];
      }
    }
    vacc += __shfl_down(vacc, 1, 64);
    vacc += __shfl_down(vacc, 2, 64);
    if (c == 0) v[(size_t)r*F_ + it*64 + ri] = vacc;
  } else if (bid < 2*NWV_ + 144) {
    int sub = bid - 2*NWV_;
    int ot = sub % 12; int it = sub / 12;
    int ri = tid >> 2, c = tid & 3;
    const float* src = wk + (size_t)(it*64 + ri)*F_ + ot*64 + c*16;
    #pragma unroll
    for (int j=0;j<4;j++){
      f32x4 v4 = *(const f32x4*)(src + j*4);
      *(f32x4*)&sbuf[ri*68 + c*16 + j*4] = v4;
    }
    __syncthreads();
    int ro = tid >> 2;
    f16 outv[16];
    #pragma unroll
    for (int j=0;j<16;j++) outv[j] = (f16)sbuf[(c*16+j)*68 + ro];
    f16* dst = wkT + (size_t)(ot*64+ro)*F_ + it*64 + c*16;
    *(f16x8*)dst = *(f16x8*)&outv[0];
    *(f16x8*)(dst+8) = *(f16x8*)&outv[8];
  } else if (bid < 2*NWV_ + 144 + 192) {
    int sub = bid - (2*NWV_ + 144);
    int st = sub & 1; int ft = (sub>>1) % 12; int b = sub / 24;
    f16* t = (f16*)sbuf;
    int sl = tid>>2, c = tid&3;
    const float* src = x + ((size_t)b*S_ + st*64 + sl)*F_ + ft*64 + c*16;
    f16 tmp[16];
    #pragma unroll
    for (int j=0;j<16;j++) tmp[j] = (f16)src[j];
    *(f16x8*)&t[sl*72 + c*16]     = *(f16x8*)&tmp[0];
    *(f16x8*)&t[sl*72 + c*16 + 8] = *(f16x8*)&tmp[8];
    __syncthreads();
    int fl = tid>>2;
    f16 outv[16];
    #pragma unroll
    for (int j=0;j<16;j++) outv[j] = t[(c*16+j)*72 + fl];
    f16* dst = h16T + ((size_t)b*F_ + ft*64 + fl)*S_ + st*64 + c*16;
    *(f16x8*)dst = *(f16x8*)&outv[0];
    *(f16x8*)(dst+8) = *(f16x8*)&outv[8];
  } else {
    int sub = bid - (2*NWV_ + 144 + 192);
    int b = sub / 24; int rem = sub % 24;
    int seg = rem >> 3, i8 = rem & 7;
    float* q_s = sbuf;
    if (tid < 96) q_s[tid] = qin[(size_t)b*F_ + i8*96 + tid];
    __syncthreads();
    int col = seg*256 + tid;
    const float* wp = wq + (size_t)(i8*96)*F_ + col;
    float a0=0.f,a1=0.f,a2=0.f,a3=0.f,a4=0.f,a5=0.f,a6=0.f,a7=0.f;
    for (int i=0;i<96;i+=8){
      a0 += q_s[i]  *wp[(size_t)(i)*F_];
      a1 += q_s[i+1]*wp[(size_t)(i+1)*F_];
      a2 += q_s[i+2]*wp[(size_t)(i+2)*F_];
      a3 += q_s[i+3]*wp[(size_t)(i+3)*F_];
      a4 += q_s[i+4]*wp[(size_t)(i+4)*F_];
      a5 += q_s[i+5]*wp[(size_t)(i+5)*F_];
      a6 += q_s[i+6]*wp[(size_t)(i+6)*F_];
      a7 += q_s[i+7]*wp[(size_t)(i+7)*F_];
    }
    qxpart[((size_t)i8*B_ + b)*F_ + col] = ((a0+a1)+(a2+a3))+((a4+a5)+(a6+a7));
  }
}

// ---------------- fused kU+kLogits (R8-proven body) ----------------
__global__ __launch_bounds__(256) void kUL(const float* __restrict__ h, const float* __restrict__ v,
                    const float* __restrict__ adj, const float* __restrict__ sb_all, int l,
                    float* __restrict__ dinv, float* __restrict__ lg) {
  int bid = blockIdx.x;           // b*R + r
  int r = bid % R_, b = bid / R_;
  __shared__ float v_s[F_];
  __shared__ float u_s[S_];
  int tid = threadIdx.x;
  #pragma unroll
  for (int j=0;j<3;j++) v_s[tid + j*256] = v[(size_t)r*F_ + tid + j*256];
  __syncthreads();
  int wid = tid>>6, lane = tid&63;
  for (int kl=0; kl<32; ++kl){
    int k = wid*32 + kl;
    const float* hr = h + ((size_t)b*S_ + k)*F_ + lane*12;
    const float* vp = &v_s[lane*12];
    float acc=0.f;
    #pragma unroll
    for (int j=0;j<3;j++){
      f32x4 a = *(const f32x4*)(hr+j*4);
      f32x4 c4 = *(const f32x4*)(vp+j*4);
      acc += a.x*c4.x+a.y*c4.y+a.z*c4.z+a.w*c4.w;
    }
    acc = wredsum(acc);
    if (lane==0) u_s[k] = acc;
  }
  __syncthreads();
  int s = tid>>1, half = tid&1;
  const float* arow = adj + ((size_t)bid*S_ + s)*S_ + half*64;
  const float* up = &u_s[half*64];
  float ssum=0.f, sdot=0.f;
  #pragma unroll
  for (int j=0;j<16;j++){
    f32x4 a = *(const f32x4*)(arow + j*4);
    ssum += a.x+a.y+a.z+a.w;
    sdot += a.x*up[j*4] + a.y*up[j*4+1] + a.z*up[j*4+2] + a.w*up[j*4+3];
  }
  ssum += __shfl_xor(ssum,1,64);
  sdot += __shfl_xor(sdot,1,64);
  if (half==0){
    float dv = (ssum==0.0f)?1.0f:(1.0f/ssum);
    dinv[(size_t)bid*S_ + s] = dv;
    lg[(size_t)bid*S_ + s] = sdot*dv + sb_all[l];
  }
}

// ---------------- kSM16 (R8-proven 64-thread body) ----------------
__global__ __launch_bounds__(64) void kSM16(const float* __restrict__ lg, const float* __restrict__ dinv,
                     const float* __restrict__ adj, f16* __restrict__ M) {
  int bid = blockIdx.x;          // b*S + s
  int b = bid >> 7, s = bid & 127;
  int lane = threadIdx.x;
  __shared__ float coef[R_];
  float x = (lane < R_) ? lg[((size_t)b*R_ + lane)*S_ + s] : -1e30f;
  float m = x;
  #pragma unroll
  for (int o=32;o;o>>=1) m = fmaxf(m, __shfl_xor(m,o,64));
  float e = (lane < R_) ? expf(x - m) : 0.f;
  float sum = e;
  #pragma unroll
  for (int o=32;o;o>>=1) sum += __shfl_xor(sum,o,64);
  if (lane < R_) coef[lane] = e/sum * SM_SCALE * dinv[((size_t)b*R_ + lane)*S_ + s];
  __syncthreads();
  for (int r=0;r<R_;r++){
    float cc = coef[r];
    size_t base = (((size_t)(b*R_+r))*S_ + s)*S_ + lane*2;
    f32x2 a2 = *(const f32x2*)(adj + base);
    f16x2 o2; o2[0]=(f16)(a2.x*cc); o2[1]=(f16)(a2.y*cc);
    *(f16x2*)(M + base) = o2;
  }
}

// ---------------- kGgemm (XCD-swizzled, R13 body) ----------------
__global__ __launch_bounds__(256) void kGgemm(const f16* __restrict__ M, const f16* __restrict__ hT, f16* __restrict__ G) {
  __shared__ f16 lds[2*16384];   // 64 KB
  f16* lsA = lds;
  f16* lsB = lds + 16384;
  int bid0 = blockIdx.x;
  int bid = (bid0 & 7) * (B_*R_*6/8) + (bid0 >> 3);
  int nt = bid % 6; int r = (bid/6) % R_; int b = bid/(6*R_);
  int tid = threadIdx.x, wid = tid>>6, lane = tid&63;
  const f16* Ab = M + (size_t)(b*R_ + r)*(S_*S_);
  const f16* Bb = hT + ((size_t)b*F_ + nt*128)*S_;
  #pragma unroll
  for (int j=0;j<8;j++){
    int qd = wid*8 + j;
    GLD16(Ab + qd*512 + lane*8, lsA + qd*512);
    GLD16(Bb + qd*512 + lane*8, lsB + qd*512);
  }
  __syncthreads();
  f32x4 acc[4][4] = {};
  int wr = wid>>1, wc = wid&1;
  int lr = lane&15, kk0 = (lane>>4)*8;
  #pragma unroll
  for (int ks=0;ks<4;ks++){
    int kk = ks*32 + kk0;
    f16x8 av[4], bv[4];
    #pragma unroll
    for (int i=0;i<4;i++) av[i] = *(const f16x8*)&lsA[(wr*64+i*16+lr)*128 + kk];
    #pragma unroll
    for (int i=0;i<4;i++) bv[i] = *(const f16x8*)&lsB[(wc*64+i*16+lr)*128 + kk];
    #pragma unroll
    for (int mi=0;mi<4;mi++)
      #pragma unroll
      for (int ni=0;ni<4;ni++)
        acc[mi][ni] = __builtin_amdgcn_mfma_f32_16x16x32_f16(av[mi],bv[ni],acc[mi][ni],0,0,0);
  }
  __syncthreads();
  #pragma unroll
  for (int mi=0;mi<4;mi++)
    #pragma unroll
    for (int ni=0;ni<4;ni++){
      int row = wr*64 + mi*16 + (lane>>4)*4;
      int col = wc*64 + ni*16 + lr;
      #pragma unroll
      for (int i=0;i<4;i++)
        lds[(row+i)*136 + col] = (f16)acc[mi][ni][i];
    }
  __syncthreads();
  int row = tid>>1, seg = tid&1;
  f16* dst = G + ((size_t)(b*R_ + r)*S_ + row)*F_ + nt*128 + seg*64;
  const f16* sl = lds + row*136 + seg*64;
  #pragma unroll
  for (int j=0;j<8;j++) *(f16x8*)(dst + j*8) = *(const f16x8*)(sl + j*8);
}

// ---------------- kOutGemm: 256x256, BK=32, 2-phase prefetch, 64KB LDS -> 2 blocks/CU ----------------
__global__ __launch_bounds__(512,2) void kOutGemm(const f16* __restrict__ G, const f16* __restrict__ WT, float* __restrict__ Cp) {
  __shared__ f16 ls[2][2][256*32];   // [buf][A/B] = 64 KB total -> 2 blocks/CU
  int bid0 = blockIdx.x;
  // bijective XCD swizzle: nwg=252, q=31, rem=4 (m204)
  int xcd = bid0 & 7, idx = bid0 >> 3;
  int bid = (xcd < 4 ? xcd*32 : 128 + (xcd-4)*31) + idx;
  int t12 = bid % 12, g = bid / 12;
  int nt = t12 % 3, mt = t12 / 3;
  int r0 = (g<20)? 2*g : 40;
  int nr = (g<20)? 2 : 1;
  int tid = threadIdx.x, wid = tid>>6, lane = tid&63;
  // staging: 2 passes/operand; wave w pass j covers rows j*128 + w*16 + (lane>>2), col (lane&3)*8
  size_t abase[2], bbase[2];
  #pragma unroll
  for (int j=0;j<2;j++){
    int arow = mt*256 + j*128 + wid*16 + (lane>>2);
    int b = arow >> 7, s = arow & 127;
    abase[j] = ((size_t)b*R_*S_ + s)*(size_t)F_ + (lane&3)*8;
    int orow = nt*256 + j*128 + wid*16 + (lane>>2);
    bbase[j] = (size_t)orow*F_ + (lane&3)*8;
  }
  f32x4 acc[8][4] = {};
  int wr = wid>>2, wc = wid&3;             // 2 (M) x 4 (N) waves, each 128x64 out
  int lr = lane&15, kk0 = (lane>>4)*8;
  int nsteps = nr*24;                      // BK=32: 24 steps per r
  auto STAGE = [&](int bf, int step){
    int r = r0 + step/24, it = step%24;
    const f16* Ar = G  + (size_t)r*S_*F_;
    const f16* Br = WT + (size_t)r*F_*F_;
    #pragma unroll
    for (int j=0;j<2;j++){
      GLD16(Ar + abase[j] + it*32, &ls[bf][0][(j*128 + wid*16)*32]);
      GLD16(Br + bbase[j] + it*32, &ls[bf][1][(j*128 + wid*16)*32]);
    }
  };
  STAGE(0, 0);
  __syncthreads();
  int cur = 0;
  for (int step=0; step<nsteps; ++step){
    if (step+1 < nsteps) STAGE(cur^1, step+1);   // prefetch next K-step
    __builtin_amdgcn_s_setprio(1);
    {
      f16x8 av[8], bv[4];
      #pragma unroll
      for (int i=0;i<8;i++) av[i] = *(const f16x8*)&ls[cur][0][(wr*128+i*16+lr)*32 + kk0];
      #pragma unroll
      for (int i=0;i<4;i++) bv[i] = *(const f16x8*)&ls[cur][1][(wc*64+i*16+lr)*32 + kk0];
      #pragma unroll
      for (int mi=0;mi<8;mi++)
        #pragma unroll
        for (int ni=0;ni<4;ni++)
          acc[mi][ni] = __builtin_amdgcn_mfma_f32_16x16x32_f16(av[mi],bv[ni],acc[mi][ni],0,0,0);
    }
    __builtin_amdgcn_s_setprio(0);
    __syncthreads();
    cur ^= 1;
  }
  #pragma unroll
  for (int mi=0;mi<8;mi++)
    #pragma unroll
    for (int ni=0;ni<4;ni++){
      int row = mt*256 + wr*128 + mi*16 + (lane>>4)*4;
      int col = nt*256 + wc*64 + ni*16 + lr;
      #pragma unroll
      for (int i=0;i<4;i++)
        Cp[((size_t)g*BS_ + row + i)*F_ + col] = acc[mi][ni][i];
    }
}

// ---------------- fused reduce + relu + f16 row + transposed f16 ----------------
__global__ __launch_bounds__(256) void kReduceT(const float* __restrict__ Cp, float* __restrict__ h32,
                                                f16* __restrict__ h16o, f16* __restrict__ hT) {
  int bid = blockIdx.x;
  int st = bid & 1; int ft = (bid>>1) % 12; int b = bid / 24;
  __shared__ f16 t[64*72];
  int tid = threadIdx.x;
  int sl = tid>>2, c = tid&3;
  size_t base = ((size_t)(b*S_ + st*64 + sl))*F_ + ft*64 + c*16;
  const float inv = 1.0f/SM_SCALE;
  f16 tmp[16];
  #pragma unroll
  for (int q=0;q<4;q++){
    f32x4 s4 = {};
    #pragma unroll
    for (int g=0; g<NG_; g++){
      f32x4 v4 = *(const f32x4*)(Cp + (size_t)g*BS_*F_ + base + q*4);
      s4.x += v4.x; s4.y += v4.y; s4.z += v4.z; s4.w += v4.w;
    }
    f32x4 rr;
    rr.x = fmaxf(s4.x*inv, 0.f); rr.y = fmaxf(s4.y*inv, 0.f);
    rr.z = fmaxf(s4.z*inv, 0.f); rr.w = fmaxf(s4.w*inv, 0.f);
    *(f32x4*)(h32 + base + q*4) = rr;
    tmp[q*4+0]=(f16)rr.x; tmp[q*4+1]=(f16)rr.y; tmp[q*4+2]=(f16)rr.z; tmp[q*4+3]=(f16)rr.w;
  }
  *(f16x8*)&t[sl*72 + c*16]     = *(f16x8*)&tmp[0];
  *(f16x8*)&t[sl*72 + c*16 + 8] = *(f16x8*)&tmp[8];
  *(f16x8*)(h16o + base)     = *(f16x8*)&tmp[0];
  *(f16x8*)(h16o + base + 8) = *(f16x8*)&tmp[8];
  __syncthreads();
  int fl = tid>>2;
  f16 outv[16];
  #pragma unroll
  for (int j=0;j<16;j++) outv[j] = t[(c*16+j)*72 + fl];
  f16* dst = hT + ((size_t)b*F_ + ft*64 + fl)*S_ + st*64 + c*16;
  *(f16x8*)dst = *(f16x8*)&outv[0];
  *(f16x8*)(dst+8) = *(f16x8*)&outv[8];
}

// ---------------- kKx (2-phase prefetch, R13 body) ----------------
__global__ __launch_bounds__(256) void kKx(const f16* __restrict__ A, const f16* __restrict__ BT,
                    const float* __restrict__ bias, float* __restrict__ C) {
  __shared__ f16 ls[2][2][128*64];
  int bid = blockIdx.x;
  int nt = bid % 6, mt = bid / 6;
  int tid = threadIdx.x, wid = tid>>6, lane = tid&63;
  size_t abase[4], bbase[4];
  #pragma unroll
  for (int j=0;j<4;j++){
    int qd = wid*4 + j;
    int row = mt*128 + qd*8 + (lane>>3);
    abase[j] = (size_t)row*F_ + (lane&7)*8;
    int o = nt*128 + qd*8 + (lane>>3);
    bbase[j] = (size_t)o*F_ + (lane&7)*8;
  }
  f32x4 acc[4][4] = {};
  int wr = wid>>1, wc = wid&1;
  int lr = lane&15, kk0 = (lane>>4)*8;
  auto STAGE = [&](int bf, int it){
    #pragma unroll
    for (int j=0;j<4;j++){
      int qd = wid*4+j;
      GLD16(A + abase[j] + it*64, &ls[bf][0][qd*512]);
      GLD16(BT + bbase[j] + it*64, &ls[bf][1][qd*512]);
    }
  };
  STAGE(0, 0);
  __syncthreads();
  int cur = 0;
  for (int it=0; it<12; ++it){
    if (it+1 < 12) STAGE(cur^1, it+1);
    #pragma unroll
    for (int ks=0;ks<2;ks++){
      int kk = ks*32 + kk0;
      f16x8 av[4], bv[4];
      #pragma unroll
      for (int i=0;i<4;i++) av[i] = *(const f16x8*)&ls[cur][0][(wr*64+i*16+lr)*64 + kk];
      #pragma unroll
      for (int i=0;i<4;i++) bv[i] = *(const f16x8*)&ls[cur][1][(wc*64+i*16+lr)*64 + kk];
      #pragma unroll
      for (int mi=0;mi<4;mi++)
        #pragma unroll
        for (int ni=0;ni<4;ni++)
          acc[mi][ni] = __builtin_amdgcn_mfma_f32_16x16x32_f16(av[mi],bv[ni],acc[mi][ni],0,0,0);
    }
    __syncthreads();
    cur ^= 1;
  }
  #pragma unroll
  for (int mi=0;mi<4;mi++)
    #pragma unroll
    for (int ni=0;ni<4;ni++){
      int row = mt*128 + wr*64 + mi*16 + (lane>>4)*4;
      int col = nt*128 + wc*64 + ni*16 + lr;
      float bb = bias[col];
      #pragma unroll
      for (int i=0;i<4;i++)
        C[(size_t)(row+i)*F_ + col] = acc[mi][ni][i] + bb;
    }
}

// ---------------- attention core per (b,h) ----------------
__global__ __launch_bounds__(256) void kAttnCore(const float* __restrict__ kx, const float* __restrict__ qxpart,
                                                 const float* __restrict__ bq, const float* __restrict__ wbil,
                                                 float* __restrict__ obuf) {
  int bid = blockIdx.x; int h = bid & 7; int b = bid >> 3;
  __shared__ float qx_s[HID_], qw_s[HID_], sc[S_];
  __shared__ float smax, ssum;
  int t = threadIdx.x;
  if (t < HID_) {
    float s = bq[h*HID_ + t];
    #pragma unroll
    for (int p=0;p<8;p++) s += qxpart[((size_t)p*B_ + b)*F_ + h*HID_ + t];
    qx_s[t] = s;
  }
  __syncthreads();
  if (t < HID_) {
    float a0=0.f,a1=0.f,a2=0.f,a3=0.f;
    for (int d=0;d<HID_;d+=4){
      a0 += qx_s[d]  *wbil[(size_t)d*HID_+t];
      a1 += qx_s[d+1]*wbil[(size_t)(d+1)*HID_+t];
      a2 += qx_s[d+2]*wbil[(size_t)(d+2)*HID_+t];
      a3 += qx_s[d+3]*wbil[(size_t)(d+3)*HID_+t];
    }
    qw_s[t] = a0+a1+a2+a3;
  }
  __syncthreads();
  {
    int k = t>>1, half = t&1;
    const float* kp = kx + ((size_t)b*S_ + k)*F_ + h*HID_ + half*48;
    const float* qp = &qw_s[half*48];
    float a0=0.f,a1=0.f;
    #pragma unroll
    for (int e=0;e<48;e+=8){
      f32x4 k0 = *(const f32x4*)(kp+e);
      f32x4 k1 = *(const f32x4*)(kp+e+4);
      a0 += k0.x*qp[e]+k0.y*qp[e+1]+k0.z*qp[e+2]+k0.w*qp[e+3];
      a1 += k1.x*qp[e+4]+k1.y*qp[e+5]+k1.z*qp[e+6]+k1.w*qp[e+7];
    }
    float s2 = a0+a1;
    s2 += __shfl_xor(s2,1,64);
    if (half==0) sc[k] = s2;
  }
  __syncthreads();
  if (t < 64) {
    float m = fmaxf(sc[t], sc[t+64]);
    #pragma unroll
    for (int o=32;o;o>>=1) m = fmaxf(m, __shfl_down(m,o,64));
    if (t==0) smax = m;
  }
  __syncthreads();
  if (t < S_) sc[t] = expf(sc[t]-smax);
  __syncthreads();
  if (t < 64) {
    float s = sc[t] + sc[t+64];
    s = wredsum(s);
    if (t==0) ssum = s;
  }
  __syncthreads();
  if (t < 192) {
    int d = t>>1, kh = (t&1)*64;
    const float* kp = kx + ((size_t)b*S_ + kh)*F_ + h*HID_ + d;
    float a0=0.f,a1=0.f,a2=0.f,a3=0.f;
    #pragma unroll
    for (int k=0;k<64;k+=4){
      a0 += sc[kh+k]  *kp[(size_t)k*F_];
      a1 += sc[kh+k+1]*kp[(size_t)(k+1)*F_];
      a2 += sc[kh+k+2]*kp[(size_t)(k+2)*F_];
      a3 += sc[kh+k+3]*kp[(size_t)(k+3)*F_];
    }
    float s2 = a0+a1+a2+a3;
    s2 += __shfl_xor(s2,1,64);
    if ((t&1)==0) obuf[(size_t)b*F_ + h*HID_ + d] = s2/ssum;
  }
}

// ---------------- final projection ----------------
__global__ __launch_bounds__(256) void kProj(const float* __restrict__ obuf, const float* __restrict__ wproj,
                      const float* __restrict__ bproj, float* __restrict__ outp) {
  int bid = blockIdx.x; int b = bid/3, seg = bid%3;
  int t = threadIdx.x;
  __shared__ float ov[F_];
  for (int j=t;j<F_;j+=256) ov[j] = obuf[(size_t)b*F_ + j];
  __syncthreads();
  int col = seg*256 + t;
  float a0=0.f,a1=0.f,a2=0.f,a3=0.f;
  for (int j=0;j<F_;j+=4){
    a0 += ov[j]*wproj[(size_t)j*F_+col];
    a1 += ov[j+1]*wproj[(size_t)(j+1)*F_+col];
    a2 += ov[j+2]*wproj[(size_t)(j+2)*F_+col];
    a3 += ov[j+3]*wproj[(size_t)(j+3)*F_+col];
  }
  outp[(size_t)b*F_ + col] = bproj[col] + a0+a1+a2+a3;
}

extern "C" void kernel_launch(void* const* d_in, const int* in_sizes, int n_in,
                              void* d_out, int out_size, void* d_ws, size_t ws_size,
                              hipStream_t stream) {
  (void)in_sizes; (void)n_in; (void)out_size;
  const float* x      = (const float*)d_in[0];
  const float* adj    = (const float*)d_in[1];
  const float* qin    = (const float*)d_in[2];
  const float* w_rgcn = (const float*)d_in[3];
  const float* score_w= (const float*)d_in[4];
  const float* score_b= (const float*)d_in[5];
  const float* wk     = (const float*)d_in[6];
  const float* bk     = (const float*)d_in[7];
  const float* wq     = (const float*)d_in[8];
  const float* bq     = (const float*)d_in[9];
  const float* wbil   = (const float*)d_in[10];
  const float* wproj  = (const float*)d_in[11];
  const float* bproj  = (const float*)d_in[12];
  float* outp = (float*)d_out;

  char* p = (char*)d_ws;
  auto alloc = [&](size_t bytes)->char* {
    char* r = p; p += (bytes + 255) & ~(size_t)255; return r;
  };
  f16*   w16T0 = (f16*)  alloc((size_t)R_*F_*F_*2);
  f16*   w16T1 = (f16*)  alloc((size_t)R_*F_*F_*2);
  f16*   G16   = (f16*)  alloc((size_t)B_*R_*S_*F_*2);
  f16*   M16   = (f16*)  alloc((size_t)B_*R_*S_*S_*2);
  float* Cpart = (float*)alloc((size_t)NG_*BS_*F_*4);
  float* h32a  = (float*)alloc((size_t)BS_*F_*4);
  f16*   h16row= (f16*)  alloc((size_t)BS_*F_*2);
  f16*   h16T  = (f16*)  alloc((size_t)BS_*F_*2);
  float* kx    = (float*)alloc((size_t)BS_*F_*4);
  f16*   wkT   = (f16*)  alloc((size_t)F_*F_*2);
  float* vbuf0 = (float*)alloc((size_t)R_*F_*4);
  float* vbuf1 = (float*)alloc((size_t)R_*F_*4);
  float* dinv  = (float*)alloc((size_t)B_*R_*S_*4);
  float* lgb   = (float*)alloc((size_t)B_*R_*S_*4);
  float* qxpart= (float*)alloc((size_t)8*B_*F_*4);
  float* obuf  = (float*)alloc((size_t)B_*F_*4);
  if ((size_t)(p - (char*)d_ws) > ws_size) return;

  // ---- prep ----
  kPrep<<<2*NWV_ + 144 + 192 + 192, 256, 0, stream>>>(
      w_rgcn, score_w, wk, x, qin, wq,
      w16T0, w16T1, vbuf0, vbuf1, wkT, h16T, qxpart);

  // ---- layer 0 (h = x) ----
  kUL<<<B_*R_, 256, 0, stream>>>(x, vbuf0, adj, score_b, 0, dinv, lgb);
  kSM16<<<B_*S_, 64, 0, stream>>>(lgb, dinv, adj, M16);
  kGgemm<<<B_*R_*6, 256, 0, stream>>>(M16, h16T, G16);
  kOutGemm<<<12*NG_, 512, 0, stream>>>(G16, w16T0, Cpart);
  kReduceT<<<192, 256, 0, stream>>>(Cpart, h32a, h16row, h16T);

  // ---- layer 1 (h = h32a) ----
  kUL<<<B_*R_, 256, 0, stream>>>(h32a, vbuf1, adj, score_b, 1, dinv, lgb);
  kSM16<<<B_*S_, 64, 0, stream>>>(lgb, dinv, adj, M16);
  kGgemm<<<B_*R_*6, 256, 0, stream>>>(M16, h16T, G16);
  kOutGemm<<<12*NG_, 512, 0, stream>>>(G16, w16T1, Cpart);
  kReduceT<<<192, 256, 0, stream>>>(Cpart, h32a, h16row, h16T);

  // ---- attention ----
  kKx<<<48, 256, 0, stream>>>(h16row, wkT, bk, kx);
  kAttnCore<<<64, 256, 0, stream>>>(kx, qxpart, bq, wbil, obuf);
  kProj<<<24, 256, 0, stream>>>(obuf, wproj, bproj, outp);
}

// Round 15
// 459.188 us; speedup vs baseline: 1.0386x; 1.0386x over previous
//
#include <hip/hip_runtime.h>
#include <stdint.h>

#define B_ 8
#define S_ 128
#define R_ 41
#define F_ 768
#define NH_ 8
#define HID_ 96
#define BS_ (B_*S_)
#define SM_SCALE 256.0f
#define NG_ 21   // split-K groups in kOutGemm (20 x 2r + 1 x 1r)
#define NWV_ (R_*12)

typedef _Float16 f16;
typedef _Float16 f16x8 __attribute__((ext_vector_type(8)));
typedef _Float16 f16x4 __attribute__((ext_vector_type(4)));
typedef _Float16 f16x2 __attribute__((ext_vector_type(2)));
typedef float f32x4 __attribute__((ext_vector_type(4)));
typedef float f32x2 __attribute__((ext_vector_type(2)));

#define GLD16(gp, lp) __builtin_amdgcn_global_load_lds((const __attribute__((address_space(1))) uint32_t*)(gp), (__attribute__((address_space(3))) uint32_t*)(lp), 16, 0, 0)

__device__ __forceinline__ float wredsum(float v){
  #pragma unroll
  for (int o=32;o;o>>=1) v += __shfl_down(v,o,64);
  return v;
}

// ================ kPrep: input-only work ================
// [0,984): w_rgcn conv+v (reg-prefetch + LDS double-buffer, 1 barrier/iter);
// [984,1128): wk->wkT; [1128,1320): x->h16T; [1320,1512): qx partials 8-way
__global__ __launch_bounds__(256) void kPrep(const float* __restrict__ w_rgcn, const float* __restrict__ score_w,
                                             const float* __restrict__ wk, const float* __restrict__ x,
                                             const float* __restrict__ qin, const float* __restrict__ wq,
                                             f16* __restrict__ wT0, f16* __restrict__ wT1,
                                             float* __restrict__ v0, float* __restrict__ v1,
                                             f16* __restrict__ wkT, f16* __restrict__ h16T,
                                             float* __restrict__ qxpart) {
  __shared__ float sbuf[2*64*68];   // 34.8 KB (w-branch dbuf; other branches use the front)
  int bid = blockIdx.x;
  int tid = threadIdx.x;
  if (bid < 2*NWV_) {
    int l = (bid >= NWV_);
    int sub = bid - l*NWV_;
    const float* w = w_rgcn + (size_t)l*R_*F_*F_;
    const float* sw = score_w + l*F_;
    f16* wT = l ? wT1 : wT0;
    float* v = l ? v1 : v0;
    int it = sub % 12, r = sub / 12;
    int ri = tid >> 2, c = tid & 3;
    const float* srow = w + ((size_t)r*F_ + (it*64 + ri))*F_ + c*16;
    float vacc = 0.f;
    f32x4 cur[4];
    #pragma unroll
    for (int j=0;j<4;j++) cur[j] = *(const f32x4*)(srow + j*4);
    int ro = tid >> 2;
    for (int ot = 0; ot < 12; ++ot) {
      float* buf = &sbuf[(ot&1)*64*68];
      f32x4 nxt[4];
      if (ot < 11) {
        const float* nsrc = srow + (ot+1)*64;
        #pragma unroll
        for (int j=0;j<4;j++) nxt[j] = *(const f32x4*)(nsrc + j*4);   // in flight across barrier
      }
      const float* swp = sw + ot*64 + c*16;
      #pragma unroll
      for (int j=0;j<4;j++){
        f32x4 s4 = *(const f32x4*)(swp + j*4);
        vacc += cur[j].x*s4.x + cur[j].y*s4.y + cur[j].z*s4.z + cur[j].w*s4.w;
      }
      #pragma unroll
      for (int j=0;j<4;j++) *(f32x4*)&buf[ri*68 + c*16 + j*4] = cur[j];
      __syncthreads();   // single barrier: buf[ot&1] stores done; prior reads of other buf precede this in program order
      f16 outv[16];
      #pragma unroll
      for (int j=0;j<16;j++) outv[j] = (f16)buf[(c*16+j)*68 + ro];
      f16* dst = wT + ((size_t)r*F_ + (ot*64+ro))*F_ + it*64 + c*16;
      *(f16x8*)dst = *(f16x8*)&outv[0];
      *(f16x8*)(dst+8) = *(f16x8*)&outv[8];
      if (ot < 11) {
        #pragma unroll
        for (int j=0;j<4;j++) cur[j] = nxt[j];
      }
    }
    vacc += __shfl_down(vacc, 1, 64);
    vacc += __shfl_down(vacc, 2, 64);
    if (c == 0) v[(size_t)r*F_ + it*64 + ri] = vacc;
  } else if (bid < 2*NWV_ + 144) {
    int sub = bid - 2*NWV_;
    int ot = sub % 12; int it = sub / 12;
    int ri = tid >> 2, c = tid & 3;
    const float* src = wk + (size_t)(it*64 + ri)*F_ + ot*64 + c*16;
    #pragma unroll
    for (int j=0;j<4;j++){
      f32x4 v4 = *(const f32x4*)(src + j*4);
      *(f32x4*)&sbuf[ri*68 + c*16 + j*4] = v4;
    }
    __syncthreads();
    int ro = tid >> 2;
    f16 outv[16];
    #pragma unroll
    for (int j=0;j<16;j++) outv[j] = (f16)sbuf[(c*16+j)*68 + ro];
    f16* dst = wkT + (size_t)(ot*64+ro)*F_ + it*64 + c*16;
    *(f16x8*)dst = *(f16x8*)&outv[0];
    *(f16x8*)(dst+8) = *(f16x8*)&outv[8];
  } else if (bid < 2*NWV_ + 144 + 192) {
    int sub = bid - (2*NWV_ + 144);
    int st = sub & 1; int ft = (sub>>1) % 12; int b = sub / 24;
    f16* t = (f16*)sbuf;
    int sl = tid>>2, c = tid&3;
    const float* src = x + ((size_t)b*S_ + st*64 + sl)*F_ + ft*64 + c*16;
    f16 tmp[16];
    #pragma unroll
    for (int j=0;j<16;j++) tmp[j] = (f16)src[j];
    *(f16x8*)&t[sl*72 + c*16]     = *(f16x8*)&tmp[0];
    *(f16x8*)&t[sl*72 + c*16 + 8] = *(f16x8*)&tmp[8];
    __syncthreads();
    int fl = tid>>2;
    f16 outv[16];
    #pragma unroll
    for (int j=0;j<16;j++) outv[j] = t[(c*16+j)*72 + fl];
    f16* dst = h16T + ((size_t)b*F_ + ft*64 + fl)*S_ + st*64 + c*16;
    *(f16x8*)dst = *(f16x8*)&outv[0];
    *(f16x8*)(dst+8) = *(f16x8*)&outv[8];
  } else {
    // qx partial: block = (b, seg, i8); i in [i8*96, i8*96+96), col = seg*256+tid
    int sub = bid - (2*NWV_ + 144 + 192);
    int b = sub / 24; int rem = sub % 24;
    int seg = rem >> 3, i8 = rem & 7;
    float* q_s = sbuf;
    if (tid < 96) q_s[tid] = qin[(size_t)b*F_ + i8*96 + tid];
    __syncthreads();
    int col = seg*256 + tid;
    const float* wp = wq + (size_t)(i8*96)*F_ + col;
    float a0=0.f,a1=0.f,a2=0.f,a3=0.f,a4=0.f,a5=0.f,a6=0.f,a7=0.f;
    for (int i=0;i<96;i+=8){
      a0 += q_s[i]  *wp[(size_t)(i)*F_];
      a1 += q_s[i+1]*wp[(size_t)(i+1)*F_];
      a2 += q_s[i+2]*wp[(size_t)(i+2)*F_];
      a3 += q_s[i+3]*wp[(size_t)(i+3)*F_];
      a4 += q_s[i+4]*wp[(size_t)(i+4)*F_];
      a5 += q_s[i+5]*wp[(size_t)(i+5)*F_];
      a6 += q_s[i+6]*wp[(size_t)(i+6)*F_];
      a7 += q_s[i+7]*wp[(size_t)(i+7)*F_];
    }
    qxpart[((size_t)i8*B_ + b)*F_ + col] = ((a0+a1)+(a2+a3))+((a4+a5)+(a6+a7));
  }
}

// ---------------- fused kU+kLogits (R8-proven body) ----------------
__global__ __launch_bounds__(256) void kUL(const float* __restrict__ h, const float* __restrict__ v,
                    const float* __restrict__ adj, const float* __restrict__ sb_all, int l,
                    float* __restrict__ dinv, float* __restrict__ lg) {
  int bid = blockIdx.x;           // b*R + r
  int r = bid % R_, b = bid / R_;
  __shared__ float v_s[F_];
  __shared__ float u_s[S_];
  int tid = threadIdx.x;
  #pragma unroll
  for (int j=0;j<3;j++) v_s[tid + j*256] = v[(size_t)r*F_ + tid + j*256];
  __syncthreads();
  int wid = tid>>6, lane = tid&63;
  for (int kl=0; kl<32; ++kl){
    int k = wid*32 + kl;
    const float* hr = h + ((size_t)b*S_ + k)*F_ + lane*12;
    const float* vp = &v_s[lane*12];
    float acc=0.f;
    #pragma unroll
    for (int j=0;j<3;j++){
      f32x4 a = *(const f32x4*)(hr+j*4);
      f32x4 c4 = *(const f32x4*)(vp+j*4);
      acc += a.x*c4.x+a.y*c4.y+a.z*c4.z+a.w*c4.w;
    }
    acc = wredsum(acc);
    if (lane==0) u_s[k] = acc;
  }
  __syncthreads();
  int s = tid>>1, half = tid&1;
  const float* arow = adj + ((size_t)bid*S_ + s)*S_ + half*64;
  const float* up = &u_s[half*64];
  float ssum=0.f, sdot=0.f;
  #pragma unroll
  for (int j=0;j<16;j++){
    f32x4 a = *(const f32x4*)(arow + j*4);
    ssum += a.x+a.y+a.z+a.w;
    sdot += a.x*up[j*4] + a.y*up[j*4+1] + a.z*up[j*4+2] + a.w*up[j*4+3];
  }
  ssum += __shfl_xor(ssum,1,64);
  sdot += __shfl_xor(sdot,1,64);
  if (half==0){
    float dv = (ssum==0.0f)?1.0f:(1.0f/ssum);
    dinv[(size_t)bid*S_ + s] = dv;
    lg[(size_t)bid*S_ + s] = sdot*dv + sb_all[l];
  }
}

// ---------------- kSM16 (R8-proven 64-thread body) ----------------
__global__ __launch_bounds__(64) void kSM16(const float* __restrict__ lg, const float* __restrict__ dinv,
                     const float* __restrict__ adj, f16* __restrict__ M) {
  int bid = blockIdx.x;          // b*S + s
  int b = bid >> 7, s = bid & 127;
  int lane = threadIdx.x;
  __shared__ float coef[R_];
  float x = (lane < R_) ? lg[((size_t)b*R_ + lane)*S_ + s] : -1e30f;
  float m = x;
  #pragma unroll
  for (int o=32;o;o>>=1) m = fmaxf(m, __shfl_xor(m,o,64));
  float e = (lane < R_) ? expf(x - m) : 0.f;
  float sum = e;
  #pragma unroll
  for (int o=32;o;o>>=1) sum += __shfl_xor(sum,o,64);
  if (lane < R_) coef[lane] = e/sum * SM_SCALE * dinv[((size_t)b*R_ + lane)*S_ + s];
  __syncthreads();
  for (int r=0;r<R_;r++){
    float cc = coef[r];
    size_t base = (((size_t)(b*R_+r))*S_ + s)*S_ + lane*2;
    f32x2 a2 = *(const f32x2*)(adj + base);
    f16x2 o2; o2[0]=(f16)(a2.x*cc); o2[1]=(f16)(a2.y*cc);
    *(f16x2*)(M + base) = o2;
  }
}

// ---------------- kGgemm (XCD-swizzled blockIdx; 1968 % 8 == 0) ----------------
__global__ __launch_bounds__(256) void kGgemm(const f16* __restrict__ M, const f16* __restrict__ hT, f16* __restrict__ G) {
  __shared__ f16 lds[2*16384];   // 64 KB
  f16* lsA = lds;
  f16* lsB = lds + 16384;
  int bid0 = blockIdx.x;
  int bid = (bid0 & 7) * (B_*R_*6/8) + (bid0 >> 3);   // XCD chunking: each XCD gets contiguous range
  int nt = bid % 6; int r = (bid/6) % R_; int b = bid/(6*R_);
  int tid = threadIdx.x, wid = tid>>6, lane = tid&63;
  const f16* Ab = M + (size_t)(b*R_ + r)*(S_*S_);
  const f16* Bb = hT + ((size_t)b*F_ + nt*128)*S_;
  #pragma unroll
  for (int j=0;j<8;j++){
    int qd = wid*8 + j;
    GLD16(Ab + qd*512 + lane*8, lsA + qd*512);
    GLD16(Bb + qd*512 + lane*8, lsB + qd*512);
  }
  __syncthreads();
  f32x4 acc[4][4] = {};
  int wr = wid>>1, wc = wid&1;
  int lr = lane&15, kk0 = (lane>>4)*8;
  #pragma unroll
  for (int ks=0;ks<4;ks++){
    int kk = ks*32 + kk0;
    f16x8 av[4], bv[4];
    #pragma unroll
    for (int i=0;i<4;i++) av[i] = *(const f16x8*)&lsA[(wr*64+i*16+lr)*128 + kk];
    #pragma unroll
    for (int i=0;i<4;i++) bv[i] = *(const f16x8*)&lsB[(wc*64+i*16+lr)*128 + kk];
    #pragma unroll
    for (int mi=0;mi<4;mi++)
      #pragma unroll
      for (int ni=0;ni<4;ni++)
        acc[mi][ni] = __builtin_amdgcn_mfma_f32_16x16x32_f16(av[mi],bv[ni],acc[mi][ni],0,0,0);
  }
  __syncthreads();
  #pragma unroll
  for (int mi=0;mi<4;mi++)
    #pragma unroll
    for (int ni=0;ni<4;ni++){
      int row = wr*64 + mi*16 + (lane>>4)*4;
      int col = wc*64 + ni*16 + lr;
      #pragma unroll
      for (int i=0;i<4;i++)
        lds[(row+i)*136 + col] = (f16)acc[mi][ni][i];
    }
  __syncthreads();
  int row = tid>>1, seg = tid&1;
  f16* dst = G + ((size_t)(b*R_ + r)*S_ + row)*F_ + nt*128 + seg*64;
  const f16* sl = lds + row*136 + seg*64;
  #pragma unroll
  for (int j=0;j<8;j++) *(f16x8*)(dst + j*8) = *(const f16x8*)(sl + j*8);
}

// ---------------- kOutGemm (256x256, BK=64, 2-phase prefetch, bijective XCD swizzle m204) ----------------
__global__ __launch_bounds__(512,2) void kOutGemm(const f16* __restrict__ G, const f16* __restrict__ WT, float* __restrict__ Cp) {
  __shared__ f16 ls[2][2][256*64];   // 128 KB
  int bid0 = blockIdx.x;
  // bijective XCD swizzle: nwg=252, q=31, rem=4 (m204)
  int xcd = bid0 & 7, idx = bid0 >> 3;
  int bid = (xcd < 4 ? xcd*32 : 128 + (xcd-4)*31) + idx;
  int t12 = bid % 12, g = bid / 12;
  int nt = t12 % 3, mt = t12 / 3;
  int r0 = (g<20)? 2*g : 40;
  int nr = (g<20)? 2 : 1;
  int tid = threadIdx.x, wid = tid>>6, lane = tid&63;
  size_t abase[4], bbase[4];
  #pragma unroll
  for (int j=0;j<4;j++){
    int chunk = wid*4 + j;
    int arow = mt*256 + chunk*8 + (lane>>3);
    int b = arow >> 7, s = arow & 127;
    abase[j] = ((size_t)b*R_*S_ + s)*(size_t)F_ + (lane&7)*8;
    int orow = nt*256 + chunk*8 + (lane>>3);
    bbase[j] = (size_t)orow*F_ + (lane&7)*8;
  }
  f32x4 acc[8][4] = {};
  int wr = wid>>2, wc = wid&3;
  int lr = lane&15, kk0 = (lane>>4)*8;
  int nsteps = nr*12;
  auto STAGE = [&](int bf, int step){
    int r = r0 + step/12, it = step%12;
    const f16* Ar = G  + (size_t)r*S_*F_;
    const f16* Br = WT + (size_t)r*F_*F_;
    #pragma unroll
    for (int j=0;j<4;j++){
      int chunk = wid*4 + j;
      GLD16(Ar + abase[j] + it*64, &ls[bf][0][chunk*512]);
      GLD16(Br + bbase[j] + it*64, &ls[bf][1][chunk*512]);
    }
  };
  STAGE(0, 0);
  __syncthreads();
  int cur = 0;
  for (int step=0; step<nsteps; ++step){
    if (step+1 < nsteps) STAGE(cur^1, step+1);
    __builtin_amdgcn_s_setprio(1);
    #pragma unroll
    for (int ks=0;ks<2;ks++){
      int kk = ks*32 + kk0;
      f16x8 av[8], bv[4];
      #pragma unroll
      for (int i=0;i<8;i++) av[i] = *(const f16x8*)&ls[cur][0][(wr*128+i*16+lr)*64 + kk];
      #pragma unroll
      for (int i=0;i<4;i++) bv[i] = *(const f16x8*)&ls[cur][1][(wc*64+i*16+lr)*64 + kk];
      #pragma unroll
      for (int mi=0;mi<8;mi++)
        #pragma unroll
        for (int ni=0;ni<4;ni++)
          acc[mi][ni] = __builtin_amdgcn_mfma_f32_16x16x32_f16(av[mi],bv[ni],acc[mi][ni],0,0,0);
    }
    __builtin_amdgcn_s_setprio(0);
    __syncthreads();
    cur ^= 1;
  }
  #pragma unroll
  for (int mi=0;mi<8;mi++)
    #pragma unroll
    for (int ni=0;ni<4;ni++){
      int row = mt*256 + wr*128 + mi*16 + (lane>>4)*4;
      int col = nt*256 + wc*64 + ni*16 + lr;
      #pragma unroll
      for (int i=0;i<4;i++)
        Cp[((size_t)g*BS_ + row + i)*F_ + col] = acc[mi][ni][i];
    }
}

// ---------------- fused reduce + relu + f16 row + transposed f16 ----------------
__global__ __launch_bounds__(256) void kReduceT(const float* __restrict__ Cp, float* __restrict__ h32,
                                                f16* __restrict__ h16o, f16* __restrict__ hT) {
  int bid = blockIdx.x;
  int st = bid & 1; int ft = (bid>>1) % 12; int b = bid / 24;
  __shared__ f16 t[64*72];
  int tid = threadIdx.x;
  int sl = tid>>2, c = tid&3;
  size_t base = ((size_t)(b*S_ + st*64 + sl))*F_ + ft*64 + c*16;
  const float inv = 1.0f/SM_SCALE;
  f16 tmp[16];
  #pragma unroll
  for (int q=0;q<4;q++){
    f32x4 s4 = {};
    #pragma unroll
    for (int g=0; g<NG_; g++){
      f32x4 v4 = *(const f32x4*)(Cp + (size_t)g*BS_*F_ + base + q*4);
      s4.x += v4.x; s4.y += v4.y; s4.z += v4.z; s4.w += v4.w;
    }
    f32x4 rr;
    rr.x = fmaxf(s4.x*inv, 0.f); rr.y = fmaxf(s4.y*inv, 0.f);
    rr.z = fmaxf(s4.z*inv, 0.f); rr.w = fmaxf(s4.w*inv, 0.f);
    *(f32x4*)(h32 + base + q*4) = rr;
    tmp[q*4+0]=(f16)rr.x; tmp[q*4+1]=(f16)rr.y; tmp[q*4+2]=(f16)rr.z; tmp[q*4+3]=(f16)rr.w;
  }
  *(f16x8*)&t[sl*72 + c*16]     = *(f16x8*)&tmp[0];
  *(f16x8*)&t[sl*72 + c*16 + 8] = *(f16x8*)&tmp[8];
  *(f16x8*)(h16o + base)     = *(f16x8*)&tmp[0];
  *(f16x8*)(h16o + base + 8) = *(f16x8*)&tmp[8];
  __syncthreads();
  int fl = tid>>2;
  f16 outv[16];
  #pragma unroll
  for (int j=0;j<16;j++) outv[j] = t[(c*16+j)*72 + fl];
  f16* dst = hT + ((size_t)b*F_ + ft*64 + fl)*S_ + st*64 + c*16;
  *(f16x8*)dst = *(f16x8*)&outv[0];
  *(f16x8*)(dst+8) = *(f16x8*)&outv[8];
}

// ---------------- kKx (2-phase prefetch) ----------------
__global__ __launch_bounds__(256) void kKx(const f16* __restrict__ A, const f16* __restrict__ BT,
                    const float* __restrict__ bias, float* __restrict__ C) {
  __shared__ f16 ls[2][2][128*64];
  int bid = blockIdx.x;
  int nt = bid % 6, mt = bid / 6;
  int tid = threadIdx.x, wid = tid>>6, lane = tid&63;
  size_t abase[4], bbase[4];
  #pragma unroll
  for (int j=0;j<4;j++){
    int qd = wid*4 + j;
    int row = mt*128 + qd*8 + (lane>>3);
    abase[j] = (size_t)row*F_ + (lane&7)*8;
    int o = nt*128 + qd*8 + (lane>>3);
    bbase[j] = (size_t)o*F_ + (lane&7)*8;
  }
  f32x4 acc[4][4] = {};
  int wr = wid>>1, wc = wid&1;
  int lr = lane&15, kk0 = (lane>>4)*8;
  auto STAGE = [&](int bf, int it){
    #pragma unroll
    for (int j=0;j<4;j++){
      int qd = wid*4+j;
      GLD16(A + abase[j] + it*64, &ls[bf][0][qd*512]);
      GLD16(BT + bbase[j] + it*64, &ls[bf][1][qd*512]);
    }
  };
  STAGE(0, 0);
  __syncthreads();
  int cur = 0;
  for (int it=0; it<12; ++it){
    if (it+1 < 12) STAGE(cur^1, it+1);
    #pragma unroll
    for (int ks=0;ks<2;ks++){
      int kk = ks*32 + kk0;
      f16x8 av[4], bv[4];
      #pragma unroll
      for (int i=0;i<4;i++) av[i] = *(const f16x8*)&ls[cur][0][(wr*64+i*16+lr)*64 + kk];
      #pragma unroll
      for (int i=0;i<4;i++) bv[i] = *(const f16x8*)&ls[cur][1][(wc*64+i*16+lr)*64 + kk];
      #pragma unroll
      for (int mi=0;mi<4;mi++)
        #pragma unroll
        for (int ni=0;ni<4;ni++)
          acc[mi][ni] = __builtin_amdgcn_mfma_f32_16x16x32_f16(av[mi],bv[ni],acc[mi][ni],0,0,0);
    }
    __syncthreads();
    cur ^= 1;
  }
  #pragma unroll
  for (int mi=0;mi<4;mi++)
    #pragma unroll
    for (int ni=0;ni<4;ni++){
      int row = mt*128 + wr*64 + mi*16 + (lane>>4)*4;
      int col = nt*128 + wc*64 + ni*16 + lr;
      float bb = bias[col];
      #pragma unroll
      for (int i=0;i<4;i++)
        C[(size_t)(row+i)*F_ + col] = acc[mi][ni][i] + bb;
    }
}

// ---------------- attention core per (b,h) ----------------
__global__ __launch_bounds__(256) void kAttnCore(const float* __restrict__ kx, const float* __restrict__ qxpart,
                                                 const float* __restrict__ bq, const float* __restrict__ wbil,
                                                 float* __restrict__ obuf) {
  int bid = blockIdx.x; int h = bid & 7; int b = bid >> 3;
  __shared__ float qx_s[HID_], qw_s[HID_], sc[S_];
  __shared__ float smax, ssum;
  int t = threadIdx.x;
  if (t < HID_) {
    float s = bq[h*HID_ + t];
    #pragma unroll
    for (int p=0;p<8;p++) s += qxpart[((size_t)p*B_ + b)*F_ + h*HID_ + t];
    qx_s[t] = s;
  }
  __syncthreads();
  if (t < HID_) {
    float a0=0.f,a1=0.f,a2=0.f,a3=0.f;
    for (int d=0;d<HID_;d+=4){
      a0 += qx_s[d]  *wbil[(size_t)d*HID_+t];
      a1 += qx_s[d+1]*wbil[(size_t)(d+1)*HID_+t];
      a2 += qx_s[d+2]*wbil[(size_t)(d+2)*HID_+t];
      a3 += qx_s[d+3]*wbil[(size_t)(d+3)*HID_+t];
    }
    qw_s[t] = a0+a1+a2+a3;
  }
  __syncthreads();
  {
    int k = t>>1, half = t&1;
    const float* kp = kx + ((size_t)b*S_ + k)*F_ + h*HID_ + half*48;
    const float* qp = &qw_s[half*48];
    float a0=0.f,a1=0.f;
    #pragma unroll
    for (int e=0;e<48;e+=8){
      f32x4 k0 = *(const f32x4*)(kp+e);
      f32x4 k1 = *(const f32x4*)(kp+e+4);
      a0 += k0.x*qp[e]+k0.y*qp[e+1]+k0.z*qp[e+2]+k0.w*qp[e+3];
      a1 += k1.x*qp[e+4]+k1.y*qp[e+5]+k1.z*qp[e+6]+k1.w*qp[e+7];
    }
    float s2 = a0+a1;
    s2 += __shfl_xor(s2,1,64);
    if (half==0) sc[k] = s2;
  }
  __syncthreads();
  if (t < 64) {
    float m = fmaxf(sc[t], sc[t+64]);
    #pragma unroll
    for (int o=32;o;o>>=1) m = fmaxf(m, __shfl_down(m,o,64));
    if (t==0) smax = m;
  }
  __syncthreads();
  if (t < S_) sc[t] = expf(sc[t]-smax);
  __syncthreads();
  if (t < 64) {
    float s = sc[t] + sc[t+64];
    s = wredsum(s);
    if (t==0) ssum = s;
  }
  __syncthreads();
  if (t < 192) {
    int d = t>>1, kh = (t&1)*64;
    const float* kp = kx + ((size_t)b*S_ + kh)*F_ + h*HID_ + d;
    float a0=0.f,a1=0.f,a2=0.f,a3=0.f;
    #pragma unroll
    for (int k=0;k<64;k+=4){
      a0 += sc[kh+k]  *kp[(size_t)k*F_];
      a1 += sc[kh+k+1]*kp[(size_t)(k+1)*F_];
      a2 += sc[kh+k+2]*kp[(size_t)(k+2)*F_];
      a3 += sc[kh+k+3]*kp[(size_t)(k+3)*F_];
    }
    float s2 = a0+a1+a2+a3;
    s2 += __shfl_xor(s2,1,64);
    if ((t&1)==0) obuf[(size_t)b*F_ + h*HID_ + d] = s2/ssum;
  }
}

// ---------------- final projection ----------------
__global__ __launch_bounds__(256) void kProj(const float* __restrict__ obuf, const float* __restrict__ wproj,
                      const float* __restrict__ bproj, float* __restrict__ outp) {
  int bid = blockIdx.x; int b = bid/3, seg = bid%3;
  int t = threadIdx.x;
  __shared__ float ov[F_];
  for (int j=t;j<F_;j+=256) ov[j] = obuf[(size_t)b*F_ + j];
  __syncthreads();
  int col = seg*256 + t;
  float a0=0.f,a1=0.f,a2=0.f,a3=0.f;
  for (int j=0;j<F_;j+=4){
    a0 += ov[j]*wproj[(size_t)j*F_+col];
    a1 += ov[j+1]*wproj[(size_t)(j+1)*F_+col];
    a2 += ov[j+2]*wproj[(size_t)(j+2)*F_+col];
    a3 += ov[j+3]*wproj[(size_t)(j+3)*F_+col];
  }
  outp[(size_t)b*F_ + col] = bproj[col] + a0+a1+a2+a3;
}

extern "C" void kernel_launch(void* const* d_in, const int* in_sizes, int n_in,
                              void* d_out, int out_size, void* d_ws, size_t ws_size,
                              hipStream_t stream) {
  (void)in_sizes; (void)n_in; (void)out_size;
  const float* x      = (const float*)d_in[0];
  const float* adj    = (const float*)d_in[1];
  const float* qin    = (const float*)d_in[2];
  const float* w_rgcn = (const float*)d_in[3];
  const float* score_w= (const float*)d_in[4];
  const float* score_b= (const float*)d_in[5];
  const float* wk     = (const float*)d_in[6];
  const float* bk     = (const float*)d_in[7];
  const float* wq     = (const float*)d_in[8];
  const float* bq     = (const float*)d_in[9];
  const float* wbil   = (const float*)d_in[10];
  const float* wproj  = (const float*)d_in[11];
  const float* bproj  = (const float*)d_in[12];
  float* outp = (float*)d_out;

  char* p = (char*)d_ws;
  auto alloc = [&](size_t bytes)->char* {
    char* r = p; p += (bytes + 255) & ~(size_t)255; return r;
  };
  f16*   w16T0 = (f16*)  alloc((size_t)R_*F_*F_*2);
  f16*   w16T1 = (f16*)  alloc((size_t)R_*F_*F_*2);
  f16*   G16   = (f16*)  alloc((size_t)B_*R_*S_*F_*2);
  f16*   M16   = (f16*)  alloc((size_t)B_*R_*S_*S_*2);
  float* Cpart = (float*)alloc((size_t)NG_*BS_*F_*4);
  float* h32a  = (float*)alloc((size_t)BS_*F_*4);
  f16*   h16row= (f16*)  alloc((size_t)BS_*F_*2);
  f16*   h16T  = (f16*)  alloc((size_t)BS_*F_*2);
  float* kx    = (float*)alloc((size_t)BS_*F_*4);
  f16*   wkT   = (f16*)  alloc((size_t)F_*F_*2);
  float* vbuf0 = (float*)alloc((size_t)R_*F_*4);
  float* vbuf1 = (float*)alloc((size_t)R_*F_*4);
  float* dinv  = (float*)alloc((size_t)B_*R_*S_*4);
  float* lgb   = (float*)alloc((size_t)B_*R_*S_*4);
  float* qxpart= (float*)alloc((size_t)8*B_*F_*4);
  float* obuf  = (float*)alloc((size_t)B_*F_*4);
  if ((size_t)(p - (char*)d_ws) > ws_size) return;

  // ---- prep ----
  kPrep<<<2*NWV_ + 144 + 192 + 192, 256, 0, stream>>>(
      w_rgcn, score_w, wk, x, qin, wq,
      w16T0, w16T1, vbuf0, vbuf1, wkT, h16T, qxpart);

  // ---- layer 0 (h = x) ----
  kUL<<<B_*R_, 256, 0, stream>>>(x, vbuf0, adj, score_b, 0, dinv, lgb);
  kSM16<<<B_*S_, 64, 0, stream>>>(lgb, dinv, adj, M16);
  kGgemm<<<B_*R_*6, 256, 0, stream>>>(M16, h16T, G16);
  kOutGemm<<<12*NG_, 512, 0, stream>>>(G16, w16T0, Cpart);
  kReduceT<<<192, 256, 0, stream>>>(Cpart, h32a, h16row, h16T);

  // ---- layer 1 (h = h32a) ----
  kUL<<<B_*R_, 256, 0, stream>>>(h32a, vbuf1, adj, score_b, 1, dinv, lgb);
  kSM16<<<B_*S_, 64, 0, stream>>>(lgb, dinv, adj, M16);
  kGgemm<<<B_*R_*6, 256, 0, stream>>>(M16, h16T, G16);
  kOutGemm<<<12*NG_, 512, 0, stream>>>(G16, w16T1, Cpart);
  kReduceT<<<192, 256, 0, stream>>>(Cpart, h32a, h16row, h16T);

  // ---- attention ----
  kKx<<<48, 256, 0, stream>>>(h16row, wkT, bk, kx);
  kAttnCore<<<64, 256, 0, stream>>>(kx, qxpart, bq, wbil, obuf);
  kProj<<<24, 256, 0, stream>>>(obuf, wproj, bproj, outp);
}